// Round 18
// baseline (192.274 us; speedup 1.0000x reference)
//
#include <hip/hip_runtime.h>
#include <hip/hip_bf16.h>
#include <hip/hip_fp16.h>
#include <cstdint>
#include <cstddef>

#define NNODES 50000
#define NEDGES 800000
#define NIN    512
#define NHID   128
#define NCLS   64

#define SCAN_BLK 512
#define SCAN_NB ((NNODES + SCAN_BLK - 1) / SCAN_BLK)  // 98

#define DEG_BLOCKS ((NEDGES / 4 + 255) / 256) // 782
#define PACK_N1 (16 * 8 * 64 * 8)             // 65536
#define PACK_N2 (4 * 4 * 64 * 8)              // 8192
#define PACK_BLOCKS ((PACK_N1 + PACK_N2) / 256)  // 288

typedef __attribute__((ext_vector_type(8))) short bf16x8;
typedef __attribute__((ext_vector_type(4))) float f32x4;

static __device__ __forceinline__ ushort f2bf(float f) {
    uint32_t u = __float_as_uint(f);
    uint32_t r = (u + 0x7fffu + ((u >> 16) & 1u)) >> 16;  // RNE
    return (ushort)r;
}
static __device__ __forceinline__ float bf2f(ushort b) {
    return __uint_as_float(((uint32_t)b) << 16);
}
static __device__ __forceinline__ float h2f(ushort u) {
    _Float16 h;
    __builtin_memcpy(&h, &u, 2);
    return (float)h;
}
static __device__ __forceinline__ ushort f2h(float f) {
    _Float16 h = (_Float16)f;
    ushort u;
    __builtin_memcpy(&u, &h, 2);
    return u;
}

// generic (LDS-backed) pointer -> 32-bit LDS byte offset for inline-asm ds_read
static __device__ __forceinline__ unsigned ldsAddr(const void* p) {
    return (unsigned)(size_t)(__attribute__((address_space(3))) const void*)p;
}

// ---------------- workspace clear ----------------
__global__ void clear_kernel(int4* __restrict__ p, int n4) {
    int i = blockIdx.x * blockDim.x + threadIdx.x;
    if (i < n4) p[i] = make_int4(0, 0, 0, 0);
}

// ---------------- deg + W-pack merged (independent work, one launch) ----------------
__global__ void deg_pack_kernel(const int4* __restrict__ dst4, int* __restrict__ deg,
                                const float* __restrict__ W1, const float* __restrict__ W2,
                                ushort* __restrict__ p1, ushort* __restrict__ p2) {
    if (blockIdx.x < DEG_BLOCKS) {
        int i = blockIdx.x * 256 + threadIdx.x;
        if (i < NEDGES / 4) {
            int4 d = dst4[i];
            atomicAdd(&deg[d.x], 1);
            atomicAdd(&deg[d.y], 1);
            atomicAdd(&deg[d.z], 1);
            atomicAdd(&deg[d.w], 1);
        }
    } else {
        int t = (blockIdx.x - DEG_BLOCKS) * 256 + threadIdx.x;
        if (t < PACK_N1) {
            int j = t & 7;
            int lane = (t >> 3) & 63;
            int cf = (t >> 9) & 7;
            int ks = t >> 12;
            int k = ks * 32 + (lane >> 4) * 8 + j;
            int c = cf * 16 + (lane & 15);
            p1[t] = f2bf(W1[(size_t)k * NHID + c]);
        } else {
            int u = t - PACK_N1;
            if (u < PACK_N2) {
                int j = u & 7;
                int lane = (u >> 3) & 63;
                int cf = (u >> 9) & 3;
                int ks = u >> 11;
                int k = ks * 32 + (lane >> 4) * 8 + j;
                int c = cf * 16 + (lane & 15);
                p2[u] = f2bf(W2[(size_t)k * NCLS + c]);
            }
        }
    }
}

// phase 1: per-block sums of deg; also compute dinv (fused)
__global__ __launch_bounds__(SCAN_BLK) void scan1_kernel(const int* __restrict__ deg,
                                                         int* __restrict__ blkSum,
                                                         float* __restrict__ dinv) {
    int i = blockIdx.x * SCAN_BLK + threadIdx.x;
    int d = (i < NNODES) ? deg[i] : 0;
    if (i < NNODES) dinv[i] = rsqrtf((float)d + 1.0f);
    int v = d;
#pragma unroll
    for (int off = 32; off; off >>= 1) v += __shfl_xor(v, off, 64);
    __shared__ int ws[SCAN_BLK / 64];
    int w = threadIdx.x >> 6;
    if ((threadIdx.x & 63) == 0) ws[w] = v;
    __syncthreads();
    if (threadIdx.x == 0) {
        int s = 0;
#pragma unroll
        for (int k = 0; k < SCAN_BLK / 64; ++k) s += ws[k];
        blkSum[blockIdx.x] = s;
    }
}

// phase 2+3 merged: wave 0 computes block offset from raw blkSum; per-block scan ->
// rowptr AND cursor (cursor = rowptr copy for absolute-slot scatter)
__global__ __launch_bounds__(SCAN_BLK) void scan3_kernel(const int* __restrict__ deg,
                                                         const int* __restrict__ blkSum,
                                                         int* __restrict__ rowptr,
                                                         int* __restrict__ cursor) {
    __shared__ int ws[SCAN_BLK / 64];
    __shared__ int boffsh;
    const int lane = threadIdx.x & 63;
    const int w = threadIdx.x >> 6;
    if (w == 0) {
        int accu = 0;
        for (int k = lane; k < blockIdx.x; k += 64) accu += blkSum[k];
#pragma unroll
        for (int off = 32; off; off >>= 1) accu += __shfl_xor(accu, off, 64);
        if (lane == 0) boffsh = accu;
    }
    int i = blockIdx.x * SCAN_BLK + threadIdx.x;
    int v = (i < NNODES) ? deg[i] : 0;
    int inc = v;
#pragma unroll
    for (int off = 1; off < 64; off <<= 1) {
        int o = __shfl_up(inc, off, 64);
        if (lane >= off) inc += o;
    }
    if (lane == 63) ws[w] = inc;
    __syncthreads();
    int wpre = 0;
    for (int k = 0; k < w; ++k) wpre += ws[k];
    if (i < NNODES) {
        int rp = inc - v + wpre + boffsh;
        rowptr[i] = rp;
        cursor[i] = rp;
    }
    if (i == 0) rowptr[NNODES] = NEDGES;  // every edge has a dst
}

// csr entry: u16 src | fp16 dinv[src] << 16  (4 B/edge)
__global__ void scatter_kernel(const int* __restrict__ src, const int* __restrict__ dst,
                               int* __restrict__ cursor,
                               const float* __restrict__ dinv, uint* __restrict__ csr) {
    int e = blockIdx.x * blockDim.x + threadIdx.x;
    if (e >= NEDGES) return;
    int d = dst[e];
    int s = src[e];
    int pos = atomicAdd(&cursor[d], 1);
    csr[pos] = (uint)s | ((uint)f2h(dinv[s]) << 16);
}

// ---------------- GEMM1: xw1[50000x128](bf16) = x[50000x512](f32) @ packW1 ----------------
// Occupancy experiment (r17 ledger: gemm1 is the only phase far from its floor, and it is
// latency-exposed at 2 waves/SIMD). B resident set halved to bw[8][2] (64 VGPR) with ONE
// mid-kernel reload between chunks 3->4 (single L2 drain, fenced by sched_barrier so it
// can't hoist into chunk 3's live range); __launch_bounds__(256,3) caps VGPR at 168 ->
// 3 waves/SIMD (+50% TLP). A reg-staged depth-2 pipeline into XOR-swizzled bf16 LDS.
__global__ __launch_bounds__(256, 3) void gemm1_kernel(const float* __restrict__ A,
                                                       const ushort* __restrict__ packB,
                                                       ushort* __restrict__ C) {
    __shared__ ushort lds[2][64 * 64];  // bf16: 2 x 8 KB
    const int t = threadIdx.x;
    const int lane = t & 63;
    const int w = t >> 6;
    const int rowBase = blockIdx.x * 64;
    const int rl = lane & 15;
    const int kg = lane >> 4;

    const ushort* bbase = packB + (size_t)lane * 8;
    bf16x8 bw[8][2];
#pragma unroll
    for (int ks = 0; ks < 8; ++ks)
#pragma unroll
        for (int q = 0; q < 2; ++q)
            bw[ks][q] = *(const bf16x8*)(bbase + ks * 4096 + (2 * w + q) * 512);

    f32x4 acc[4][2];
#pragma unroll
    for (int rg = 0; rg < 4; ++rg)
#pragma unroll
        for (int q = 0; q < 2; ++q) acc[rg][q] = (f32x4)(0.f);

    const int r0 = t >> 3,         c0 = t & 7;
    const int r1 = (t + 256) >> 3, c1 = (t + 256) & 7;
    int g0 = rowBase + r0; if (g0 >= NNODES) g0 = NNODES - 1;
    int g1 = rowBase + r1; if (g1 >= NNODES) g1 = NNODES - 1;
    const float* ga0 = A + (size_t)g0 * NIN + c0 * 8;
    const float* ga1 = A + (size_t)g1 * NIN + c1 * 8;
    ushort* wd0 = &lds[0][0] + r0 * 64 + ((c0 ^ (r0 & 7)) * 8);
    ushort* wd1 = &lds[0][0] + r1 * 64 + ((c1 ^ (r1 & 7)) * 8);

    auto cvt8 = [](float4 a, float4 b) {
        bf16x8 v;
        v[0] = (short)f2bf(a.x); v[1] = (short)f2bf(a.y);
        v[2] = (short)f2bf(a.z); v[3] = (short)f2bf(a.w);
        v[4] = (short)f2bf(b.x); v[5] = (short)f2bf(b.y);
        v[6] = (short)f2bf(b.z); v[7] = (short)f2bf(b.w);
        return v;
    };

    float4 pend[2][4];
    pend[0][0] = *(const float4*)(ga0);
    pend[0][1] = *(const float4*)(ga0 + 4);
    pend[0][2] = *(const float4*)(ga1);
    pend[0][3] = *(const float4*)(ga1 + 4);
    pend[1][0] = *(const float4*)(ga0 + 64);
    pend[1][1] = *(const float4*)(ga0 + 68);
    pend[1][2] = *(const float4*)(ga1 + 64);
    pend[1][3] = *(const float4*)(ga1 + 68);
    *(bf16x8*)wd0 = cvt8(pend[0][0], pend[0][1]);
    *(bf16x8*)wd1 = cvt8(pend[0][2], pend[0][3]);
    asm volatile("s_waitcnt lgkmcnt(0)" ::: "memory");
    __builtin_amdgcn_s_barrier();

#pragma unroll
    for (int tch = 0; tch < 8; ++tch) {
        const int cur = tch & 1;
        // mid-kernel B reload: ks 8..15, placed after chunk-3 barrier, fenced both sides
        if (tch == 4) {
            __builtin_amdgcn_sched_barrier(0);
#pragma unroll
            for (int ks = 0; ks < 8; ++ks)
#pragma unroll
                for (int q = 0; q < 2; ++q)
                    bw[ks][q] = *(const bf16x8*)(bbase + (8 + ks) * 4096 + (2 * w + q) * 512);
            __builtin_amdgcn_sched_barrier(0);
        }
        if (tch + 2 < 8) {
            pend[cur][0] = *(const float4*)(ga0 + (tch + 2) * 64);
            pend[cur][1] = *(const float4*)(ga0 + (tch + 2) * 64 + 4);
            pend[cur][2] = *(const float4*)(ga1 + (tch + 2) * 64);
            pend[cur][3] = *(const float4*)(ga1 + (tch + 2) * 64 + 4);
            __builtin_amdgcn_sched_barrier(0);
        }
        const unsigned lbase = ldsAddr(&lds[cur][0]);
#pragma unroll
        for (int ks = 0; ks < 2; ++ks) {
            bf16x8 af0, af1, af2, af3;
            const unsigned sw = (unsigned)(((ks * 4 + kg) ^ (rl & 7)) * 16);
            const unsigned a0 = lbase + (unsigned)((0 * 16 + rl) * 128) + sw;
            const unsigned a1 = lbase + (unsigned)((1 * 16 + rl) * 128) + sw;
            const unsigned a2 = lbase + (unsigned)((2 * 16 + rl) * 128) + sw;
            const unsigned a3 = lbase + (unsigned)((3 * 16 + rl) * 128) + sw;
            asm volatile("ds_read_b128 %0, %1" : "=&v"(af0) : "v"(a0));
            asm volatile("ds_read_b128 %0, %1" : "=&v"(af1) : "v"(a1));
            asm volatile("ds_read_b128 %0, %1" : "=&v"(af2) : "v"(a2));
            asm volatile("ds_read_b128 %0, %1" : "=&v"(af3) : "v"(a3));
            asm volatile("s_waitcnt lgkmcnt(0)" ::: "memory");
            __builtin_amdgcn_sched_barrier(0);  // rule #18
            const int kq = (tch * 2 + ks) & 7;  // bw holds ks 0..7 then 8..15
            acc[0][0] = __builtin_amdgcn_mfma_f32_16x16x32_bf16(af0, bw[kq][0], acc[0][0], 0, 0, 0);
            acc[0][1] = __builtin_amdgcn_mfma_f32_16x16x32_bf16(af0, bw[kq][1], acc[0][1], 0, 0, 0);
            acc[1][0] = __builtin_amdgcn_mfma_f32_16x16x32_bf16(af1, bw[kq][0], acc[1][0], 0, 0, 0);
            acc[1][1] = __builtin_amdgcn_mfma_f32_16x16x32_bf16(af1, bw[kq][1], acc[1][1], 0, 0, 0);
            acc[2][0] = __builtin_amdgcn_mfma_f32_16x16x32_bf16(af2, bw[kq][0], acc[2][0], 0, 0, 0);
            acc[2][1] = __builtin_amdgcn_mfma_f32_16x16x32_bf16(af2, bw[kq][1], acc[2][1], 0, 0, 0);
            acc[3][0] = __builtin_amdgcn_mfma_f32_16x16x32_bf16(af3, bw[kq][0], acc[3][0], 0, 0, 0);
            acc[3][1] = __builtin_amdgcn_mfma_f32_16x16x32_bf16(af3, bw[kq][1], acc[3][1], 0, 0, 0);
        }
        if (tch + 1 < 8) {
            const int nxt = cur ^ 1;
            *(bf16x8*)(wd0 + nxt * 4096) = cvt8(pend[nxt][0], pend[nxt][1]);
            *(bf16x8*)(wd1 + nxt * 4096) = cvt8(pend[nxt][2], pend[nxt][3]);
        }
        asm volatile("s_waitcnt lgkmcnt(0)" ::: "memory");
        __builtin_amdgcn_s_barrier();
    }

    // C/D: col = lane&15, row = (lane>>4)*4 + j   [m89-verified]
#pragma unroll
    for (int rg = 0; rg < 4; ++rg)
#pragma unroll
        for (int q = 0; q < 2; ++q)
#pragma unroll
            for (int j = 0; j < 4; ++j) {
                int rr = rowBase + rg * 16 + kg * 4 + j;
                if (rr < NNODES)
                    C[(size_t)rr * NHID + (2 * w + q) * 16 + rl] = f2bf(acc[rg][q][j]);
            }
}

// ---------------- GEMM2: xw2[50000x64](bf16) = h[50000x128](bf16) @ packW2 ----------------
__global__ __launch_bounds__(256) void gemm2_kernel(const ushort* __restrict__ A,
                                                    const ushort* __restrict__ packB,
                                                    ushort* __restrict__ C) {
    int wid = (blockIdx.x * blockDim.x + threadIdx.x) >> 6;
    int lane = threadIdx.x & 63;
    int rowBase = wid * 16;
    if (rowBase >= NNODES) return;
    int rl = lane & 15;
    int kg = lane >> 4;
    const ushort* ap = A + (size_t)(rowBase + rl) * NHID + kg * 8;

    f32x4 acc[4];
#pragma unroll
    for (int cf = 0; cf < 4; ++cf) acc[cf] = (f32x4)(0.f);

#pragma unroll
    for (int ks = 0; ks < 4; ++ks) {
        bf16x8 af = *(const bf16x8*)(ap + ks * 32);
        const ushort* bp = packB + ((size_t)(ks * 4) * 64 + lane) * 8;
#pragma unroll
        for (int cf = 0; cf < 4; ++cf) {
            bf16x8 bf = *(const bf16x8*)(bp + (size_t)cf * 512);
            acc[cf] = __builtin_amdgcn_mfma_f32_16x16x32_bf16(af, bf, acc[cf], 0, 0, 0);
        }
    }
#pragma unroll
    for (int cf = 0; cf < 4; ++cf)
#pragma unroll
        for (int j = 0; j < 4; ++j)
            C[(size_t)(rowBase + kg * 4 + j) * NCLS + cf * 16 + rl] = f2bf(acc[cf][j]);
}

// ---------------- agg1: h = relu(agg(xw1) + b1), one wave per node, barrier-free ------
__global__ __launch_bounds__(256) void agg1_kernel(const ushort* __restrict__ xw,
                                                   const int* __restrict__ rowptr,
                                                   const uint* __restrict__ csr,
                                                   const float* __restrict__ dinv,
                                                   const float* __restrict__ b1,
                                                   ushort* __restrict__ h) {
    int wid = (blockIdx.x * blockDim.x + threadIdx.x) >> 6;
    int lane = threadIdx.x & 63;
    if (wid >= NNODES) return;
    int beg = rowptr[wid], end = rowptr[wid + 1];
    float a0 = 0.f, a1 = 0.f, a2 = 0.f, a3 = 0.f;
    int j = beg;
    for (; j + 16 <= end; j += 16) {
        uint e[16];
#pragma unroll
        for (int q = 0; q < 16; ++q) e[q] = csr[j + q];
        uint v[16];
#pragma unroll
        for (int q = 0; q < 16; ++q)
            v[q] = *(const uint*)&xw[(size_t)(e[q] & 0xffffu) * NHID + lane * 2];
#pragma unroll
        for (int q = 0; q < 8; ++q) {
            float wq = h2f((ushort)(e[q] >> 16));
            a0 += wq * __uint_as_float(v[q] << 16);
            a1 += wq * __uint_as_float(v[q] & 0xffff0000u);
        }
#pragma unroll
        for (int q = 8; q < 16; ++q) {
            float wq = h2f((ushort)(e[q] >> 16));
            a2 += wq * __uint_as_float(v[q] << 16);
            a3 += wq * __uint_as_float(v[q] & 0xffff0000u);
        }
    }
    for (; j + 4 <= end; j += 4) {
        uint e[4];
#pragma unroll
        for (int q = 0; q < 4; ++q) e[q] = csr[j + q];
        uint v[4];
#pragma unroll
        for (int q = 0; q < 4; ++q)
            v[q] = *(const uint*)&xw[(size_t)(e[q] & 0xffffu) * NHID + lane * 2];
#pragma unroll
        for (int q = 0; q < 4; ++q) {
            float wq = h2f((ushort)(e[q] >> 16));
            a0 += wq * __uint_as_float(v[q] << 16);
            a1 += wq * __uint_as_float(v[q] & 0xffff0000u);
        }
    }
    for (; j < end; ++j) {
        uint e = csr[j];
        float wq = h2f((ushort)(e >> 16));
        uint v = *(const uint*)&xw[(size_t)(e & 0xffffu) * NHID + lane * 2];
        a0 += wq * __uint_as_float(v << 16);
        a1 += wq * __uint_as_float(v & 0xffff0000u);
    }
    a0 += a2; a1 += a3;
    float di = dinv[wid];
    float sl = di * di;
    uint xv = *(const uint*)&xw[(size_t)wid * NHID + lane * 2];
    float2 bv = *(const float2*)&b1[lane * 2];
    float r0 = di * a0 + sl * __uint_as_float(xv << 16) + bv.x;
    float r1 = di * a1 + sl * __uint_as_float(xv & 0xffff0000u) + bv.y;
    uint o = (uint)f2bf(fmaxf(r0, 0.f)) | ((uint)f2bf(fmaxf(r1, 0.f)) << 16);
    *(uint*)&h[(size_t)wid * NHID + lane * 2] = o;
}

// ---------------- agg2 + bias + log_softmax, one wave per node, bf16 in, f32 out ------
__global__ __launch_bounds__(256) void agg2_kernel(const ushort* __restrict__ xw,
                                                   const int* __restrict__ rowptr,
                                                   const uint* __restrict__ csr,
                                                   const float* __restrict__ dinv,
                                                   const float* __restrict__ b2,
                                                   float* __restrict__ out) {
    int wid = (blockIdx.x * blockDim.x + threadIdx.x) >> 6;
    int lane = threadIdx.x & 63;
    if (wid >= NNODES) return;
    int beg = rowptr[wid], end = rowptr[wid + 1];
    float a = 0.f, b = 0.f;
    int j = beg;
    for (; j + 16 <= end; j += 16) {
        uint e[16];
#pragma unroll
        for (int q = 0; q < 16; ++q) e[q] = csr[j + q];
        float v[16];
#pragma unroll
        for (int q = 0; q < 16; ++q)
            v[q] = bf2f(xw[(size_t)(e[q] & 0xffffu) * NCLS + lane]);
#pragma unroll
        for (int q = 0; q < 8; ++q) a += h2f((ushort)(e[q] >> 16)) * v[q];
#pragma unroll
        for (int q = 8; q < 16; ++q) b += h2f((ushort)(e[q] >> 16)) * v[q];
    }
    for (; j + 4 <= end; j += 4) {
        uint e[4];
#pragma unroll
        for (int q = 0; q < 4; ++q) e[q] = csr[j + q];
        float v[4];
#pragma unroll
        for (int q = 0; q < 4; ++q)
            v[q] = bf2f(xw[(size_t)(e[q] & 0xffffu) * NCLS + lane]);
#pragma unroll
        for (int q = 0; q < 4; ++q) a += h2f((ushort)(e[q] >> 16)) * v[q];
    }
    for (; j < end; ++j) {
        uint e = csr[j];
        a += h2f((ushort)(e >> 16)) * bf2f(xw[(size_t)(e & 0xffffu) * NCLS + lane]);
    }
    a += b;
    float di = dinv[wid];
    float o = di * a + di * di * bf2f(xw[(size_t)wid * NCLS + lane]) + b2[lane];
    float m = o;
#pragma unroll
    for (int off = 32; off; off >>= 1) m = fmaxf(m, __shfl_xor(m, off, 64));
    float ex = __expf(o - m);
    float ssum = ex;
#pragma unroll
    for (int off = 32; off; off >>= 1) ssum += __shfl_xor(ssum, off, 64);
    out[(size_t)wid * NCLS + lane] = (o - m) - __logf(ssum);
}

// ---------------- launch ----------------

extern "C" void kernel_launch(void* const* d_in, const int* in_sizes, int n_in,
                              void* d_out, int out_size, void* d_ws, size_t ws_size,
                              hipStream_t stream) {
    const float* x  = (const float*)d_in[0];
    const int*   ei = (const int*)d_in[1];
    const int*   src = ei;
    const int*   dst = ei + NEDGES;
    const float* W1 = (const float*)d_in[2];
    const float* b1 = (const float*)d_in[3];
    const float* W2 = (const float*)d_in[4];
    const float* b2 = (const float*)d_in[5];
    float* out = (float*)d_out;

    char* w = (char*)d_ws;
    auto alloc = [&](size_t bytes) {
        char* p = w;
        w += (bytes + 255) & ~(size_t)255;
        return p;
    };
    int*    deg    = (int*)alloc(NNODES * 4);
    int*    cursor = (int*)alloc(NNODES * 4);
    int*    rowptr = (int*)alloc((NNODES + 1) * 4);
    int*    blkSum = (int*)alloc(SCAN_NB * 4);
    uint*   csr    = (uint*)alloc((size_t)NEDGES * 4);
    float*  dinv   = (float*)alloc(NNODES * 4);
    ushort* pack1  = (ushort*)alloc((size_t)PACK_N1 * 2);
    ushort* pack2  = (ushort*)alloc((size_t)PACK_N2 * 2);
    ushort* xw1    = (ushort*)alloc((size_t)NNODES * NHID * 2);
    ushort* h      = (ushort*)alloc((size_t)NNODES * NHID * 2);
    ushort* xw2    = (ushort*)alloc((size_t)NNODES * NCLS * 2);

    const int n4 = (NNODES + 3) / 4;  // deg only (cursor written by scan3)
    clear_kernel<<<(n4 + 255) / 256, 256, 0, stream>>>((int4*)deg, n4);

    deg_pack_kernel<<<DEG_BLOCKS + PACK_BLOCKS, 256, 0, stream>>>(
        (const int4*)dst, deg, W1, W2, pack1, pack2);
    scan1_kernel<<<SCAN_NB, SCAN_BLK, 0, stream>>>(deg, blkSum, dinv);
    scan3_kernel<<<SCAN_NB, SCAN_BLK, 0, stream>>>(deg, blkSum, rowptr, cursor);
    scatter_kernel<<<(NEDGES + 255) / 256, 256, 0, stream>>>(src, dst, cursor, dinv, csr);

    // layer 1
    gemm1_kernel<<<(NNODES + 63) / 64, 256, 0, stream>>>(x, pack1, xw1);
    agg1_kernel<<<(NNODES * 64 + 255) / 256, 256, 0, stream>>>(xw1, rowptr, csr, dinv, b1, h);

    // layer 2
    gemm2_kernel<<<(NNODES / 16 + 3) / 4, 256, 0, stream>>>(h, pack2, xw2);
    agg2_kernel<<<(NNODES * 64 + 255) / 256, 256, 0, stream>>>(xw2, rowptr, csr, dinv, b2, out);
}

// Round 19
// 185.666 us; speedup vs baseline: 1.0356x; 1.0356x over previous
//
#include <hip/hip_runtime.h>
#include <hip/hip_bf16.h>
#include <hip/hip_fp16.h>
#include <cstdint>
#include <cstddef>

#define NNODES 50000
#define NEDGES 800000
#define NIN    512
#define NHID   128
#define NCLS   64

#define SCAN_BLK 512
#define SCAN_NB ((NNODES + SCAN_BLK - 1) / SCAN_BLK)  // 98

#define DEG_BLOCKS ((NEDGES / 4 + 255) / 256) // 782
#define PACK_N1 (16 * 8 * 64 * 8)             // 65536
#define PACK_N2 (4 * 4 * 64 * 8)              // 8192
#define PACK_BLOCKS ((PACK_N1 + PACK_N2) / 256)  // 288

typedef __attribute__((ext_vector_type(8))) short bf16x8;
typedef __attribute__((ext_vector_type(4))) float f32x4;

static __device__ __forceinline__ ushort f2bf(float f) {
    uint32_t u = __float_as_uint(f);
    uint32_t r = (u + 0x7fffu + ((u >> 16) & 1u)) >> 16;  // RNE
    return (ushort)r;
}
static __device__ __forceinline__ float bf2f(ushort b) {
    return __uint_as_float(((uint32_t)b) << 16);
}
static __device__ __forceinline__ float h2f(ushort u) {
    _Float16 h;
    __builtin_memcpy(&h, &u, 2);
    return (float)h;
}
static __device__ __forceinline__ ushort f2h(float f) {
    _Float16 h = (_Float16)f;
    ushort u;
    __builtin_memcpy(&u, &h, 2);
    return u;
}

// generic (LDS-backed) pointer -> 32-bit LDS byte offset for inline-asm ds_read
static __device__ __forceinline__ unsigned ldsAddr(const void* p) {
    return (unsigned)(size_t)(__attribute__((address_space(3))) const void*)p;
}

// ---------------- workspace clear ----------------
__global__ void clear_kernel(int4* __restrict__ p, int n4) {
    int i = blockIdx.x * blockDim.x + threadIdx.x;
    if (i < n4) p[i] = make_int4(0, 0, 0, 0);
}

// ---------------- deg + W-pack merged (independent work, one launch) ----------------
__global__ void deg_pack_kernel(const int4* __restrict__ dst4, int* __restrict__ deg,
                                const float* __restrict__ W1, const float* __restrict__ W2,
                                ushort* __restrict__ p1, ushort* __restrict__ p2) {
    if (blockIdx.x < DEG_BLOCKS) {
        int i = blockIdx.x * 256 + threadIdx.x;
        if (i < NEDGES / 4) {
            int4 d = dst4[i];
            atomicAdd(&deg[d.x], 1);
            atomicAdd(&deg[d.y], 1);
            atomicAdd(&deg[d.z], 1);
            atomicAdd(&deg[d.w], 1);
        }
    } else {
        int t = (blockIdx.x - DEG_BLOCKS) * 256 + threadIdx.x;
        if (t < PACK_N1) {
            int j = t & 7;
            int lane = (t >> 3) & 63;
            int cf = (t >> 9) & 7;
            int ks = t >> 12;
            int k = ks * 32 + (lane >> 4) * 8 + j;
            int c = cf * 16 + (lane & 15);
            p1[t] = f2bf(W1[(size_t)k * NHID + c]);
        } else {
            int u = t - PACK_N1;
            if (u < PACK_N2) {
                int j = u & 7;
                int lane = (u >> 3) & 63;
                int cf = (u >> 9) & 3;
                int ks = u >> 11;
                int k = ks * 32 + (lane >> 4) * 8 + j;
                int c = cf * 16 + (lane & 15);
                p2[u] = f2bf(W2[(size_t)k * NCLS + c]);
            }
        }
    }
}

// phase 1: per-block sums of deg; also compute dinv (fused)
__global__ __launch_bounds__(SCAN_BLK) void scan1_kernel(const int* __restrict__ deg,
                                                         int* __restrict__ blkSum,
                                                         float* __restrict__ dinv) {
    int i = blockIdx.x * SCAN_BLK + threadIdx.x;
    int d = (i < NNODES) ? deg[i] : 0;
    if (i < NNODES) dinv[i] = rsqrtf((float)d + 1.0f);
    int v = d;
#pragma unroll
    for (int off = 32; off; off >>= 1) v += __shfl_xor(v, off, 64);
    __shared__ int ws[SCAN_BLK / 64];
    int w = threadIdx.x >> 6;
    if ((threadIdx.x & 63) == 0) ws[w] = v;
    __syncthreads();
    if (threadIdx.x == 0) {
        int s = 0;
#pragma unroll
        for (int k = 0; k < SCAN_BLK / 64; ++k) s += ws[k];
        blkSum[blockIdx.x] = s;
    }
}

// phase 2+3 merged: wave 0 computes block offset from raw blkSum; per-block scan ->
// rowptr AND cursor (cursor = rowptr copy for absolute-slot scatter)
__global__ __launch_bounds__(SCAN_BLK) void scan3_kernel(const int* __restrict__ deg,
                                                         const int* __restrict__ blkSum,
                                                         int* __restrict__ rowptr,
                                                         int* __restrict__ cursor) {
    __shared__ int ws[SCAN_BLK / 64];
    __shared__ int boffsh;
    const int lane = threadIdx.x & 63;
    const int w = threadIdx.x >> 6;
    if (w == 0) {
        int accu = 0;
        for (int k = lane; k < blockIdx.x; k += 64) accu += blkSum[k];
#pragma unroll
        for (int off = 32; off; off >>= 1) accu += __shfl_xor(accu, off, 64);
        if (lane == 0) boffsh = accu;
    }
    int i = blockIdx.x * SCAN_BLK + threadIdx.x;
    int v = (i < NNODES) ? deg[i] : 0;
    int inc = v;
#pragma unroll
    for (int off = 1; off < 64; off <<= 1) {
        int o = __shfl_up(inc, off, 64);
        if (lane >= off) inc += o;
    }
    if (lane == 63) ws[w] = inc;
    __syncthreads();
    int wpre = 0;
    for (int k = 0; k < w; ++k) wpre += ws[k];
    if (i < NNODES) {
        int rp = inc - v + wpre + boffsh;
        rowptr[i] = rp;
        cursor[i] = rp;
    }
    if (i == 0) rowptr[NNODES] = NEDGES;  // every edge has a dst
}

// csr entry: u16 src | fp16 dinv[src] << 16  (4 B/edge)
__global__ void scatter_kernel(const int* __restrict__ src, const int* __restrict__ dst,
                               int* __restrict__ cursor,
                               const float* __restrict__ dinv, uint* __restrict__ csr) {
    int e = blockIdx.x * blockDim.x + threadIdx.x;
    if (e >= NEDGES) return;
    int d = dst[e];
    int s = src[e];
    int pos = atomicAdd(&cursor[d], 1);
    csr[pos] = (uint)s | ((uint)f2h(dinv[s]) << 16);
}

// ---------------- GEMM1: xw1[50000x128](bf16) = x[50000x512](f32) @ packW1 ----------------
// B fragments preloaded to VGPRs; A reg-staged depth-2 pipeline into XOR-swizzled bf16 LDS.
// (r17 measured-best configuration; r18's occupancy variant was null -> reverted.)
__global__ __launch_bounds__(256, 2) void gemm1_kernel(const float* __restrict__ A,
                                                       const ushort* __restrict__ packB,
                                                       ushort* __restrict__ C) {
    __shared__ ushort lds[2][64 * 64];  // bf16: 2 x 8 KB
    const int t = threadIdx.x;
    const int lane = t & 63;
    const int w = t >> 6;
    const int rowBase = blockIdx.x * 64;
    const int rl = lane & 15;
    const int kg = lane >> 4;

    bf16x8 bw[16][2];
    {
        const ushort* bbase = packB + (size_t)lane * 8;
#pragma unroll
        for (int ks = 0; ks < 16; ++ks)
#pragma unroll
            for (int q = 0; q < 2; ++q)
                bw[ks][q] = *(const bf16x8*)(bbase + ks * 4096 + (2 * w + q) * 512);
    }

    f32x4 acc[4][2];
#pragma unroll
    for (int rg = 0; rg < 4; ++rg)
#pragma unroll
        for (int q = 0; q < 2; ++q) acc[rg][q] = (f32x4)(0.f);

    const int r0 = t >> 3,         c0 = t & 7;
    const int r1 = (t + 256) >> 3, c1 = (t + 256) & 7;
    int g0 = rowBase + r0; if (g0 >= NNODES) g0 = NNODES - 1;
    int g1 = rowBase + r1; if (g1 >= NNODES) g1 = NNODES - 1;
    const float* ga0 = A + (size_t)g0 * NIN + c0 * 8;
    const float* ga1 = A + (size_t)g1 * NIN + c1 * 8;
    ushort* wd0 = &lds[0][0] + r0 * 64 + ((c0 ^ (r0 & 7)) * 8);
    ushort* wd1 = &lds[0][0] + r1 * 64 + ((c1 ^ (r1 & 7)) * 8);

    auto cvt8 = [](float4 a, float4 b) {
        bf16x8 v;
        v[0] = (short)f2bf(a.x); v[1] = (short)f2bf(a.y);
        v[2] = (short)f2bf(a.z); v[3] = (short)f2bf(a.w);
        v[4] = (short)f2bf(b.x); v[5] = (short)f2bf(b.y);
        v[6] = (short)f2bf(b.z); v[7] = (short)f2bf(b.w);
        return v;
    };

    float4 pend[2][4];
    pend[0][0] = *(const float4*)(ga0);
    pend[0][1] = *(const float4*)(ga0 + 4);
    pend[0][2] = *(const float4*)(ga1);
    pend[0][3] = *(const float4*)(ga1 + 4);
    pend[1][0] = *(const float4*)(ga0 + 64);
    pend[1][1] = *(const float4*)(ga0 + 68);
    pend[1][2] = *(const float4*)(ga1 + 64);
    pend[1][3] = *(const float4*)(ga1 + 68);
    *(bf16x8*)wd0 = cvt8(pend[0][0], pend[0][1]);
    *(bf16x8*)wd1 = cvt8(pend[0][2], pend[0][3]);
    asm volatile("s_waitcnt lgkmcnt(0)" ::: "memory");
    __builtin_amdgcn_s_barrier();

#pragma unroll
    for (int tch = 0; tch < 8; ++tch) {
        const int cur = tch & 1;
        if (tch + 2 < 8) {
            pend[cur][0] = *(const float4*)(ga0 + (tch + 2) * 64);
            pend[cur][1] = *(const float4*)(ga0 + (tch + 2) * 64 + 4);
            pend[cur][2] = *(const float4*)(ga1 + (tch + 2) * 64);
            pend[cur][3] = *(const float4*)(ga1 + (tch + 2) * 64 + 4);
            __builtin_amdgcn_sched_barrier(0);
        }
        const unsigned lbase = ldsAddr(&lds[cur][0]);
#pragma unroll
        for (int ks = 0; ks < 2; ++ks) {
            bf16x8 af0, af1, af2, af3;
            const unsigned sw = (unsigned)(((ks * 4 + kg) ^ (rl & 7)) * 16);
            const unsigned a0 = lbase + (unsigned)((0 * 16 + rl) * 128) + sw;
            const unsigned a1 = lbase + (unsigned)((1 * 16 + rl) * 128) + sw;
            const unsigned a2 = lbase + (unsigned)((2 * 16 + rl) * 128) + sw;
            const unsigned a3 = lbase + (unsigned)((3 * 16 + rl) * 128) + sw;
            asm volatile("ds_read_b128 %0, %1" : "=&v"(af0) : "v"(a0));
            asm volatile("ds_read_b128 %0, %1" : "=&v"(af1) : "v"(a1));
            asm volatile("ds_read_b128 %0, %1" : "=&v"(af2) : "v"(a2));
            asm volatile("ds_read_b128 %0, %1" : "=&v"(af3) : "v"(a3));
            asm volatile("s_waitcnt lgkmcnt(0)" ::: "memory");
            __builtin_amdgcn_sched_barrier(0);  // rule #18
            const int kq = tch * 2 + ks;
            acc[0][0] = __builtin_amdgcn_mfma_f32_16x16x32_bf16(af0, bw[kq][0], acc[0][0], 0, 0, 0);
            acc[0][1] = __builtin_amdgcn_mfma_f32_16x16x32_bf16(af0, bw[kq][1], acc[0][1], 0, 0, 0);
            acc[1][0] = __builtin_amdgcn_mfma_f32_16x16x32_bf16(af1, bw[kq][0], acc[1][0], 0, 0, 0);
            acc[1][1] = __builtin_amdgcn_mfma_f32_16x16x32_bf16(af1, bw[kq][1], acc[1][1], 0, 0, 0);
            acc[2][0] = __builtin_amdgcn_mfma_f32_16x16x32_bf16(af2, bw[kq][0], acc[2][0], 0, 0, 0);
            acc[2][1] = __builtin_amdgcn_mfma_f32_16x16x32_bf16(af2, bw[kq][1], acc[2][1], 0, 0, 0);
            acc[3][0] = __builtin_amdgcn_mfma_f32_16x16x32_bf16(af3, bw[kq][0], acc[3][0], 0, 0, 0);
            acc[3][1] = __builtin_amdgcn_mfma_f32_16x16x32_bf16(af3, bw[kq][1], acc[3][1], 0, 0, 0);
        }
        if (tch + 1 < 8) {
            const int nxt = cur ^ 1;
            *(bf16x8*)(wd0 + nxt * 4096) = cvt8(pend[nxt][0], pend[nxt][1]);
            *(bf16x8*)(wd1 + nxt * 4096) = cvt8(pend[nxt][2], pend[nxt][3]);
        }
        asm volatile("s_waitcnt lgkmcnt(0)" ::: "memory");
        __builtin_amdgcn_s_barrier();
    }

    // C/D: col = lane&15, row = (lane>>4)*4 + j   [m89-verified]
#pragma unroll
    for (int rg = 0; rg < 4; ++rg)
#pragma unroll
        for (int q = 0; q < 2; ++q)
#pragma unroll
            for (int j = 0; j < 4; ++j) {
                int rr = rowBase + rg * 16 + kg * 4 + j;
                if (rr < NNODES)
                    C[(size_t)rr * NHID + (2 * w + q) * 16 + rl] = f2bf(acc[rg][q][j]);
            }
}

// ---------------- GEMM2: xw2[50000x64](bf16) = h[50000x128](bf16) @ packW2 ----------------
__global__ __launch_bounds__(256) void gemm2_kernel(const ushort* __restrict__ A,
                                                    const ushort* __restrict__ packB,
                                                    ushort* __restrict__ C) {
    int wid = (blockIdx.x * blockDim.x + threadIdx.x) >> 6;
    int lane = threadIdx.x & 63;
    int rowBase = wid * 16;
    if (rowBase >= NNODES) return;
    int rl = lane & 15;
    int kg = lane >> 4;
    const ushort* ap = A + (size_t)(rowBase + rl) * NHID + kg * 8;

    f32x4 acc[4];
#pragma unroll
    for (int cf = 0; cf < 4; ++cf) acc[cf] = (f32x4)(0.f);

#pragma unroll
    for (int ks = 0; ks < 4; ++ks) {
        bf16x8 af = *(const bf16x8*)(ap + ks * 32);
        const ushort* bp = packB + ((size_t)(ks * 4) * 64 + lane) * 8;
#pragma unroll
        for (int cf = 0; cf < 4; ++cf) {
            bf16x8 bf = *(const bf16x8*)(bp + (size_t)cf * 512);
            acc[cf] = __builtin_amdgcn_mfma_f32_16x16x32_bf16(af, bf, acc[cf], 0, 0, 0);
        }
    }
#pragma unroll
    for (int cf = 0; cf < 4; ++cf)
#pragma unroll
        for (int j = 0; j < 4; ++j)
            C[(size_t)(rowBase + kg * 4 + j) * NCLS + cf * 16 + rl] = f2bf(acc[cf][j]);
}

// ---------------- agg1: h = relu(agg(xw1) + b1), one wave per node, barrier-free ------
__global__ __launch_bounds__(256) void agg1_kernel(const ushort* __restrict__ xw,
                                                   const int* __restrict__ rowptr,
                                                   const uint* __restrict__ csr,
                                                   const float* __restrict__ dinv,
                                                   const float* __restrict__ b1,
                                                   ushort* __restrict__ h) {
    int wid = (blockIdx.x * blockDim.x + threadIdx.x) >> 6;
    int lane = threadIdx.x & 63;
    if (wid >= NNODES) return;
    int beg = rowptr[wid], end = rowptr[wid + 1];
    float a0 = 0.f, a1 = 0.f, a2 = 0.f, a3 = 0.f;
    int j = beg;
    for (; j + 16 <= end; j += 16) {
        uint e[16];
#pragma unroll
        for (int q = 0; q < 16; ++q) e[q] = csr[j + q];
        uint v[16];
#pragma unroll
        for (int q = 0; q < 16; ++q)
            v[q] = *(const uint*)&xw[(size_t)(e[q] & 0xffffu) * NHID + lane * 2];
#pragma unroll
        for (int q = 0; q < 8; ++q) {
            float wq = h2f((ushort)(e[q] >> 16));
            a0 += wq * __uint_as_float(v[q] << 16);
            a1 += wq * __uint_as_float(v[q] & 0xffff0000u);
        }
#pragma unroll
        for (int q = 8; q < 16; ++q) {
            float wq = h2f((ushort)(e[q] >> 16));
            a2 += wq * __uint_as_float(v[q] << 16);
            a3 += wq * __uint_as_float(v[q] & 0xffff0000u);
        }
    }
    for (; j + 4 <= end; j += 4) {
        uint e[4];
#pragma unroll
        for (int q = 0; q < 4; ++q) e[q] = csr[j + q];
        uint v[4];
#pragma unroll
        for (int q = 0; q < 4; ++q)
            v[q] = *(const uint*)&xw[(size_t)(e[q] & 0xffffu) * NHID + lane * 2];
#pragma unroll
        for (int q = 0; q < 4; ++q) {
            float wq = h2f((ushort)(e[q] >> 16));
            a0 += wq * __uint_as_float(v[q] << 16);
            a1 += wq * __uint_as_float(v[q] & 0xffff0000u);
        }
    }
    for (; j < end; ++j) {
        uint e = csr[j];
        float wq = h2f((ushort)(e >> 16));
        uint v = *(const uint*)&xw[(size_t)(e & 0xffffu) * NHID + lane * 2];
        a0 += wq * __uint_as_float(v << 16);
        a1 += wq * __uint_as_float(v & 0xffff0000u);
    }
    a0 += a2; a1 += a3;
    float di = dinv[wid];
    float sl = di * di;
    uint xv = *(const uint*)&xw[(size_t)wid * NHID + lane * 2];
    float2 bv = *(const float2*)&b1[lane * 2];
    float r0 = di * a0 + sl * __uint_as_float(xv << 16) + bv.x;
    float r1 = di * a1 + sl * __uint_as_float(xv & 0xffff0000u) + bv.y;
    uint o = (uint)f2bf(fmaxf(r0, 0.f)) | ((uint)f2bf(fmaxf(r1, 0.f)) << 16);
    *(uint*)&h[(size_t)wid * NHID + lane * 2] = o;
}

// ---------------- agg2 + bias + log_softmax, one wave per node, bf16 in, f32 out ------
__global__ __launch_bounds__(256) void agg2_kernel(const ushort* __restrict__ xw,
                                                   const int* __restrict__ rowptr,
                                                   const uint* __restrict__ csr,
                                                   const float* __restrict__ dinv,
                                                   const float* __restrict__ b2,
                                                   float* __restrict__ out) {
    int wid = (blockIdx.x * blockDim.x + threadIdx.x) >> 6;
    int lane = threadIdx.x & 63;
    if (wid >= NNODES) return;
    int beg = rowptr[wid], end = rowptr[wid + 1];
    float a = 0.f, b = 0.f;
    int j = beg;
    for (; j + 16 <= end; j += 16) {
        uint e[16];
#pragma unroll
        for (int q = 0; q < 16; ++q) e[q] = csr[j + q];
        float v[16];
#pragma unroll
        for (int q = 0; q < 16; ++q)
            v[q] = bf2f(xw[(size_t)(e[q] & 0xffffu) * NCLS + lane]);
#pragma unroll
        for (int q = 0; q < 8; ++q) a += h2f((ushort)(e[q] >> 16)) * v[q];
#pragma unroll
        for (int q = 8; q < 16; ++q) b += h2f((ushort)(e[q] >> 16)) * v[q];
    }
    for (; j + 4 <= end; j += 4) {
        uint e[4];
#pragma unroll
        for (int q = 0; q < 4; ++q) e[q] = csr[j + q];
        float v[4];
#pragma unroll
        for (int q = 0; q < 4; ++q)
            v[q] = bf2f(xw[(size_t)(e[q] & 0xffffu) * NCLS + lane]);
#pragma unroll
        for (int q = 0; q < 4; ++q) a += h2f((ushort)(e[q] >> 16)) * v[q];
    }
    for (; j < end; ++j) {
        uint e = csr[j];
        a += h2f((ushort)(e >> 16)) * bf2f(xw[(size_t)(e & 0xffffu) * NCLS + lane]);
    }
    a += b;
    float di = dinv[wid];
    float o = di * a + di * di * bf2f(xw[(size_t)wid * NCLS + lane]) + b2[lane];
    float m = o;
#pragma unroll
    for (int off = 32; off; off >>= 1) m = fmaxf(m, __shfl_xor(m, off, 64));
    float ex = __expf(o - m);
    float ssum = ex;
#pragma unroll
    for (int off = 32; off; off >>= 1) ssum += __shfl_xor(ssum, off, 64);
    out[(size_t)wid * NCLS + lane] = (o - m) - __logf(ssum);
}

// ---------------- launch ----------------

extern "C" void kernel_launch(void* const* d_in, const int* in_sizes, int n_in,
                              void* d_out, int out_size, void* d_ws, size_t ws_size,
                              hipStream_t stream) {
    const float* x  = (const float*)d_in[0];
    const int*   ei = (const int*)d_in[1];
    const int*   src = ei;
    const int*   dst = ei + NEDGES;
    const float* W1 = (const float*)d_in[2];
    const float* b1 = (const float*)d_in[3];
    const float* W2 = (const float*)d_in[4];
    const float* b2 = (const float*)d_in[5];
    float* out = (float*)d_out;

    char* w = (char*)d_ws;
    auto alloc = [&](size_t bytes) {
        char* p = w;
        w += (bytes + 255) & ~(size_t)255;
        return p;
    };
    int*    deg    = (int*)alloc(NNODES * 4);
    int*    cursor = (int*)alloc(NNODES * 4);
    int*    rowptr = (int*)alloc((NNODES + 1) * 4);
    int*    blkSum = (int*)alloc(SCAN_NB * 4);
    uint*   csr    = (uint*)alloc((size_t)NEDGES * 4);
    float*  dinv   = (float*)alloc(NNODES * 4);
    ushort* pack1  = (ushort*)alloc((size_t)PACK_N1 * 2);
    ushort* pack2  = (ushort*)alloc((size_t)PACK_N2 * 2);
    ushort* xw1    = (ushort*)alloc((size_t)NNODES * NHID * 2);
    ushort* h      = (ushort*)alloc((size_t)NNODES * NHID * 2);
    ushort* xw2    = (ushort*)alloc((size_t)NNODES * NCLS * 2);

    const int n4 = (NNODES + 3) / 4;  // deg only (cursor written by scan3)
    clear_kernel<<<(n4 + 255) / 256, 256, 0, stream>>>((int4*)deg, n4);

    deg_pack_kernel<<<DEG_BLOCKS + PACK_BLOCKS, 256, 0, stream>>>(
        (const int4*)dst, deg, W1, W2, pack1, pack2);
    scan1_kernel<<<SCAN_NB, SCAN_BLK, 0, stream>>>(deg, blkSum, dinv);
    scan3_kernel<<<SCAN_NB, SCAN_BLK, 0, stream>>>(deg, blkSum, rowptr, cursor);
    scatter_kernel<<<(NEDGES + 255) / 256, 256, 0, stream>>>(src, dst, cursor, dinv, csr);

    // layer 1
    gemm1_kernel<<<(NNODES + 63) / 64, 256, 0, stream>>>(x, pack1, xw1);
    agg1_kernel<<<(NNODES * 64 + 255) / 256, 256, 0, stream>>>(xw1, rowptr, csr, dinv, b1, h);

    // layer 2
    gemm2_kernel<<<(NNODES / 16 + 3) / 4, 256, 0, stream>>>(h, pack2, xw2);
    agg2_kernel<<<(NNODES * 64 + 255) / 256, 256, 0, stream>>>(xw2, rowptr, csr, dinv, b2, out);
}